// Round 5
// baseline (100.551 us; speedup 1.0000x reference)
//
#include <hip/hip_runtime.h>

// f = -grad_p sum(mlp(p)); mlp: 2->8 relu ->4 relu ->2 (no bias on last).
// Force is PIECEWISE CONSTANT in p (depends only on the 12 ReLU sign bits).
// The harness's np reference runs fp32; we replicate OpenBLAS sgemm op order
// bit-exactly (k-ascending fma from 0, bias as separate add) -> absmax 0.0
// verified in R3. DO NOT reorder the forward arithmetic or enable fast-math.
//
// Perf: streaming 33.5 MB in / 33.5 MB out, floor ~10.6 us. This version:
// 4 positions (2x 16B vectors) per thread, nontemporal load/store (zero reuse).
// NOTE: __builtin_nontemporal_* rejects HIP_vector_type (struct); use clang
// native ext_vector_type instead.
//
// Layouts (row-major, per JAX): W1 [8,2], b1 [8], W2 [4,8], b2 [4], W3 [2,4]

typedef float f32x4 __attribute__((ext_vector_type(4)));

__global__ __launch_bounds__(256) void toy_force_kernel(
    const f32x4* __restrict__ pos4,
    const float* __restrict__ W1,
    const float* __restrict__ b1,
    const float* __restrict__ W2,
    const float* __restrict__ b2,
    const float* __restrict__ W3,
    f32x4* __restrict__ out4,
    int n4)
{
    // Uniform weight loads -> scalar loads, L1-resident.
    float w1x[8], w1y[8], bb1[8];
    float w2[4][8], bb2[4], g2base[4];
#pragma unroll
    for (int k = 0; k < 8; ++k) {
        w1x[k] = W1[2 * k];
        w1y[k] = W1[2 * k + 1];
        bb1[k] = b1[k];
    }
#pragma unroll
    for (int j = 0; j < 4; ++j) {
#pragma unroll
        for (int k = 0; k < 8; ++k) w2[j][k] = W2[8 * j + k];
        bb2[j]    = b2[j];
        g2base[j] = W3[j] + W3[4 + j];   // ones @ W3 (dE/dh2 before relu mask)
    }

    int i0 = (blockIdx.x * blockDim.x + threadIdx.x) * 2;
    if (i0 >= n4) return;

    f32x4 pa = __builtin_nontemporal_load(pos4 + i0);
    f32x4 pb = __builtin_nontemporal_load(pos4 + i0 + 1);

    float pin[8] = {pa.x, pa.y, pa.z, pa.w, pb.x, pb.y, pb.z, pb.w};
    float pout[8];

#pragma unroll
    for (int t = 0; t < 4; ++t) {
        float px = pin[2 * t];
        float py = pin[2 * t + 1];

        // --- layer 1, numpy/sgemm bit-exact:
        // dot = fma(py,w1, RN(px*w0)); bias is a separate add. (verified 0.0)
        float z1[8], a1[8];
#pragma unroll
        for (int k = 0; k < 8; ++k) {
            float dot = fmaf(py, w1y[k], px * w1x[k]);
            z1[k] = dot + bb1[k];
            a1[k] = fmaxf(z1[k], 0.0f);
        }

        // --- layer 2, numpy/sgemm bit-exact: k-ascending fma from 0, + bias.
        float g2[4];
#pragma unroll
        for (int j = 0; j < 4; ++j) {
            float acc = 0.0f;
#pragma unroll
            for (int k = 0; k < 8; ++k) acc = fmaf(a1[k], w2[j][k], acc);
            float z2 = acc + bb2[j];
            g2[j] = (z2 > 0.0f) ? g2base[j] : 0.0f;
        }

        // --- backward (piecewise-constant in weights), any fp32 order.
        float fx = 0.0f, fy = 0.0f;
#pragma unroll
        for (int k = 0; k < 8; ++k) {
            float g1 = 0.0f;
#pragma unroll
            for (int j = 0; j < 4; ++j) g1 = fmaf(g2[j], w2[j][k], g1);
            g1 = (z1[k] > 0.0f) ? g1 : 0.0f;
            fx = fmaf(g1, w1x[k], fx);
            fy = fmaf(g1, w1y[k], fy);
        }

        pout[2 * t]     = -fx;
        pout[2 * t + 1] = -fy;
    }

    f32x4 oa = {pout[0], pout[1], pout[2], pout[3]};
    f32x4 ob = {pout[4], pout[5], pout[6], pout[7]};
    __builtin_nontemporal_store(oa, out4 + i0);
    __builtin_nontemporal_store(ob, out4 + i0 + 1);
}

extern "C" void kernel_launch(void* const* d_in, const int* in_sizes, int n_in,
                              void* d_out, int out_size, void* d_ws, size_t ws_size,
                              hipStream_t stream) {
    const float* pos = (const float*)d_in[0];
    const float* W1  = (const float*)d_in[1];
    const float* b1  = (const float*)d_in[2];
    const float* W2  = (const float*)d_in[3];
    const float* b2  = (const float*)d_in[4];
    const float* W3  = (const float*)d_in[5];
    float* out = (float*)d_out;

    int n4 = in_sizes[0] / 4;                  // 2,097,152 16B vectors
    int threads_needed = n4 / 2;               // 2 vectors per thread
    int block = 256;
    int grid = (threads_needed + block - 1) / block;   // 4096 blocks

    toy_force_kernel<<<grid, block, 0, stream>>>(
        (const f32x4*)pos, W1, b1, W2, b2, W3, (f32x4*)out, n4);
}

// Round 6
// 97.804 us; speedup vs baseline: 1.0281x; 1.0281x over previous
//
#include <hip/hip_runtime.h>

// f = -grad_p sum(mlp(p)); mlp: 2->8 relu ->4 relu ->2 (no bias on last).
// Force is PIECEWISE CONSTANT in p (depends only on the 12 ReLU sign bits).
// The harness's np reference runs fp32; we replicate OpenBLAS sgemm op order
// bit-exactly (k-ascending fma from 0, bias as separate add) -> absmax 0.0
// verified in R3/R5. DO NOT reorder the forward arithmetic or use fast-math.
//
// Perf: streaming 33.5 MB in / 33.5 MB out, kernel floor ~10.6 us @6.3 TB/s.
// Measured dur_us (~94-100) is dominated by the harness's per-iteration reset
// (256 MiB d_ws poison ~42 us + d_out poison + input restores, ~50 dispatches);
// the kernel never appears in rocprof top-5 (< 42 us). This version: R3's
// 1-float4/thread shape (32k waves, best latency hiding) + nontemporal
// load/store (zero-reuse stream; ext_vector_type needed for the builtin).
//
// Layouts (row-major, per JAX): W1 [8,2], b1 [8], W2 [4,8], b2 [4], W3 [2,4]

typedef float f32x4 __attribute__((ext_vector_type(4)));

__global__ __launch_bounds__(256) void toy_force_kernel(
    const f32x4* __restrict__ pos4,
    const float* __restrict__ W1,
    const float* __restrict__ b1,
    const float* __restrict__ W2,
    const float* __restrict__ b2,
    const float* __restrict__ W3,
    f32x4* __restrict__ out4,
    int n4)
{
    // Uniform weight loads -> scalar s_loads, L1-resident, SGPR-held.
    float w1x[8], w1y[8], bb1[8];
    float w2[4][8], bb2[4], g2base[4];
#pragma unroll
    for (int k = 0; k < 8; ++k) {
        w1x[k] = W1[2 * k];
        w1y[k] = W1[2 * k + 1];
        bb1[k] = b1[k];
    }
#pragma unroll
    for (int j = 0; j < 4; ++j) {
#pragma unroll
        for (int k = 0; k < 8; ++k) w2[j][k] = W2[8 * j + k];
        bb2[j]    = b2[j];
        g2base[j] = W3[j] + W3[4 + j];   // ones @ W3 (dE/dh2 before relu mask)
    }

    int i = blockIdx.x * blockDim.x + threadIdx.x;
    if (i >= n4) return;

    f32x4 p = __builtin_nontemporal_load(pos4 + i);
    float pin[4]  = {p.x, p.y, p.z, p.w};
    float pout[4];

#pragma unroll
    for (int t = 0; t < 2; ++t) {
        float px = pin[2 * t];
        float py = pin[2 * t + 1];

        // --- layer 1, numpy/sgemm bit-exact:
        // dot = fma(py,w1, RN(px*w0)); bias is a separate add. (verified 0.0)
        float z1[8], a1[8];
#pragma unroll
        for (int k = 0; k < 8; ++k) {
            float dot = fmaf(py, w1y[k], px * w1x[k]);
            z1[k] = dot + bb1[k];
            a1[k] = fmaxf(z1[k], 0.0f);
        }

        // --- layer 2, numpy/sgemm bit-exact: k-ascending fma from 0, + bias.
        float g2[4];
#pragma unroll
        for (int j = 0; j < 4; ++j) {
            float acc = 0.0f;
#pragma unroll
            for (int k = 0; k < 8; ++k) acc = fmaf(a1[k], w2[j][k], acc);
            float z2 = acc + bb2[j];
            g2[j] = (z2 > 0.0f) ? g2base[j] : 0.0f;
        }

        // --- backward (piecewise-constant in weights), any fp32 order.
        float fx = 0.0f, fy = 0.0f;
#pragma unroll
        for (int k = 0; k < 8; ++k) {
            float g1 = 0.0f;
#pragma unroll
            for (int j = 0; j < 4; ++j) g1 = fmaf(g2[j], w2[j][k], g1);
            g1 = (z1[k] > 0.0f) ? g1 : 0.0f;
            fx = fmaf(g1, w1x[k], fx);
            fy = fmaf(g1, w1y[k], fy);
        }

        pout[2 * t]     = -fx;
        pout[2 * t + 1] = -fy;
    }

    f32x4 o = {pout[0], pout[1], pout[2], pout[3]};
    __builtin_nontemporal_store(o, out4 + i);
}

extern "C" void kernel_launch(void* const* d_in, const int* in_sizes, int n_in,
                              void* d_out, int out_size, void* d_ws, size_t ws_size,
                              hipStream_t stream) {
    const float* pos = (const float*)d_in[0];
    const float* W1  = (const float*)d_in[1];
    const float* b1  = (const float*)d_in[2];
    const float* W2  = (const float*)d_in[3];
    const float* b2  = (const float*)d_in[4];
    const float* W3  = (const float*)d_in[5];
    float* out = (float*)d_out;

    int n4 = in_sizes[0] / 4;              // 2,097,152 16B vectors (2 pos each)
    int block = 256;
    int grid = (n4 + block - 1) / block;   // 8192 blocks

    toy_force_kernel<<<grid, block, 0, stream>>>(
        (const f32x4*)pos, W1, b1, W2, b2, W3, (f32x4*)out, n4);
}